// Round 6
// baseline (80.709 us; speedup 1.0000x reference)
//
#include <hip/hip_runtime.h>

// Cochlea: per-f compress + first-order IIR (alpha=0.9) along T + ReLU.
// B=32, T=4096, F=64.
//
// Round-6 design: ZERO read amplification via depth-1 neighbor exchange.
// The carry-in of block tb is I_{tb-1} = A_{tb-1} + a^256 * I_{tb-2}, and
// a^256 ~ 2e-12 -> carry-in == predecessor's LOCAL aggregate (no chain).
// Block = 16 segments x 32 f2-lanes (512 thr, 8 waves), TBLK=256, all
// segments produce output. Each thread scans L=16 rows (y0=0) into regs,
// carries combine in-block (unrolled predicated Horner over LDS). Block
// aggregate A is published via d_ws (device-scope atomics + flag); only
// segments 0..5 need a^(16s)*A_prev (a^96*|A| ~ 5e-5 beyond), so 5 of 8
// waves never spin. tb==0 uses the virtual carry A_prev = compressed[t=0]
// (y_{-1}=c0 reproduces y0=c0 exactly). Flags reset per launch by
// hipMemsetAsync. All 512 blocks co-resident (16 waves/CU, VGPR<=128).

typedef float vf2 __attribute__((ext_vector_type(2)));

namespace {
constexpr int kB    = 32;
constexpr int kT    = 4096;
constexpr int kF2   = 32;              // 64 floats = 32 vf2 per row
constexpr int kL    = 16;              // t-steps per segment
constexpr int kSEG  = 16;              // segments per block (all output)
constexpr int kTBLK = kSEG * kL;       // 256 rows per block
constexpr int kNTB  = kT / kTBLK;      // 16 T-blocks per b
constexpr int kNEED = 6;               // segments that apply A_prev
constexpr float kA   = 0.9f;
constexpr float kOmA = 1.0f - kA;

constexpr float apow(int n) { float r = 1.f; for (int i = 0; i < n; ++i) r *= 0.9f; return r; }
constexpr float kA16 = apow(kL);       // alpha^16

// d_ws layout: A values [b][tb][64] floats, then flags [b][tb] ints.
constexpr size_t kAFloats  = (size_t)kB * kNTB * 64;          // 32768
constexpr size_t kFlagOff  = kAFloats * sizeof(float);        // 128 KiB
constexpr size_t kFlagSize = (size_t)kB * kNTB * sizeof(int); // 2 KiB
}

__global__ __launch_bounds__(kSEG * kF2, 4) void cochlea_kernel(
    const vf2* __restrict__ spec,
    const vf2* __restrict__ ftune,
    const float* __restrict__ thr_p,
    const float* __restrict__ ratio_p,
    vf2* __restrict__ out,
    float* __restrict__ ws_A,
    int* __restrict__ ws_flag)
{
    const int tid = threadIdx.x;
    const int f2  = tid & (kF2 - 1);
    const int seg = tid >> 5;                 // 0..15, wave = 2 segments
    const int tb  = blockIdx.x & (kNTB - 1);
    const int b   = blockIdx.x >> 4;

    const float thr   = thr_p[0];
    const float ratio = ratio_p[0];
    const vf2 ft = ftune[f2];

    const int tseg = tb * kTBLK + seg * kL;   // this thread's first row
    const size_t rowbase = (size_t)b * kT * kF2 + f2;
    const vf2* sp = spec + rowbase + (size_t)tseg * kF2;

    // ---- local scan: 16 rows, y0 = 0, staged loads ----
    vf2 xv[kL];
    #pragma unroll
    for (int j = 0; j < kL; ++j) xv[j] = sp[(size_t)j * kF2];

    vf2 y  = {0.f, 0.f};
    vf2 v0 = {0.f, 0.f};
    vf2 r[kL];
    #pragma unroll
    for (int j = 0; j < kL; ++j) {
        float ta = xv[j].x * ft.x;
        float tc = xv[j].y * ft.y;
        float ca = fmaf(ta - thr, ratio, thr);
        float cc = fmaf(tc - thr, ratio, thr);
        vf2 v;
        v.x = (ta > thr) ? ca : ta;
        v.y = (tc > thr) ? cc : tc;
        if (j == 0) v0 = v;
        y.x = fmaf(kA, y.x, kOmA * v.x);
        y.y = fmaf(kA, y.y, kOmA * v.y);
        r[j] = y;
    }

    __shared__ vf2 lds_c[kSEG][kF2];
    __shared__ vf2 lds_v0[kF2];
    lds_c[seg][f2] = y;
    if (tb == 0 && seg == 0) lds_v0[f2] = v0;  // virtual carry for tb==0
    __syncthreads();

    // ---- in-block combine: yin = sum_{j<seg} A16^(seg-1-j) * C_j ----
    // Fully unrolled + predicated; LDS reads batch, no serial runtime loop.
    vf2 yin = {0.f, 0.f};
    float a16s = 1.f;                          // alpha^(16*seg)
    #pragma unroll
    for (int j = 0; j < kSEG - 1; ++j) {
        vf2 c = lds_c[j][f2];
        if (j < seg) {
            yin.x = fmaf(kA16, yin.x, c.x);
            yin.y = fmaf(kA16, yin.y, c.y);
            a16s *= kA16;
        }
    }

    // ---- publish block aggregate A = A16*H_15 + C_15 (seg 15 owns it) ----
    if (seg == kSEG - 1) {
        vf2 A;
        A.x = fmaf(kA16, yin.x, y.x);
        A.y = fmaf(kA16, yin.y, y.y);
        float* Ap = ws_A + ((size_t)(b * kNTB + tb)) * 64 + 2 * f2;
        __hip_atomic_store(Ap + 0, A.x, __ATOMIC_RELAXED, __HIP_MEMORY_SCOPE_AGENT);
        __hip_atomic_store(Ap + 1, A.y, __ATOMIC_RELAXED, __HIP_MEMORY_SCOPE_AGENT);
        __threadfence();                       // wave-level vmcnt drain + L2 wb
        if (f2 == 0)
            __hip_atomic_store(&ws_flag[b * kNTB + tb], 1,
                               __ATOMIC_RELEASE, __HIP_MEMORY_SCOPE_AGENT);
    }

    // ---- early segments fold in the neighbor carry ----
    if (seg < kNEED) {
        vf2 aprev;
        if (tb == 0) {
            aprev = lds_v0[f2];
        } else {
            int* fl = ws_flag + (b * kNTB + tb - 1);
            while (__hip_atomic_load(fl, __ATOMIC_ACQUIRE,
                                     __HIP_MEMORY_SCOPE_AGENT) == 0)
                __builtin_amdgcn_s_sleep(2);
            const float* Ap = ws_A + ((size_t)(b * kNTB + tb - 1)) * 64 + 2 * f2;
            aprev.x = __hip_atomic_load(Ap + 0, __ATOMIC_RELAXED, __HIP_MEMORY_SCOPE_AGENT);
            aprev.y = __hip_atomic_load(Ap + 1, __ATOMIC_RELAXED, __HIP_MEMORY_SCOPE_AGENT);
        }
        yin.x = fmaf(a16s, aprev.x, yin.x);
        yin.y = fmaf(a16s, aprev.y, yin.y);
    }
    // seg >= kNEED: dropped term <= a^96 * |A| ~ 5e-5 << 2.78e-2 threshold.

    // ---- fixup + store: out[j] = relu(r[j] + a^(j+1) * yin) ----
    vf2* op = out + rowbase + (size_t)tseg * kF2;
    float ap = kA;
    #pragma unroll
    for (int j = 0; j < kL; ++j) {
        vf2 o;
        o.x = fmaxf(fmaf(ap, yin.x, r[j].x), 0.f);
        o.y = fmaxf(fmaf(ap, yin.y, r[j].y), 0.f);
        __builtin_nontemporal_store(o, op + (size_t)j * kF2);
        ap *= kA;
    }
}

extern "C" void kernel_launch(void* const* d_in, const int* in_sizes, int n_in,
                              void* d_out, int out_size, void* d_ws, size_t ws_size,
                              hipStream_t stream) {
    const vf2*   spec  = (const vf2*)d_in[0];
    const vf2*   ftune = (const vf2*)d_in[1];
    const float* thr   = (const float*)d_in[2];
    const float* ratio = (const float*)d_in[3];
    vf2*  out    = (vf2*)d_out;
    float* ws_A  = (float*)d_ws;
    int* ws_flag = (int*)((char*)d_ws + kFlagOff);

    // Reset exchange flags every launch (graph-capturable, deterministic).
    hipMemsetAsync(ws_flag, 0, kFlagSize, stream);

    dim3 grid(kB * kNTB), block(kSEG * kF2);   // 512 blocks x 512 threads
    cochlea_kernel<<<grid, block, 0, stream>>>(spec, ftune, thr, ratio, out,
                                               ws_A, ws_flag);
}

// Round 7
// 16.097 us; speedup vs baseline: 5.0140x; 5.0140x over previous
//
#include <hip/hip_runtime.h>

// Cochlea: per-f compress + first-order IIR (alpha=0.9) along T + ReLU.
// B=32, T=4096, F=64.
//
// Round-7: revert round-6's cross-block flag exchange (agent-scope spin
// across non-coherent XCD L2s collapsed BW: 80.7us). Instead each block
// WALKS 2 consecutive 256-row tiles; the carry crosses tiles in registers
// (exact). Warm-up (64 steps, alpha^64 ~ 1.2e-3 truncation) paid once per
// 512 output rows -> read amplification 1.125x. Warm-up is uniform: every
// seg scans 4 warm rows; combine via A4-Horner. Tile-1 loads are issued
// BEFORE tile-0's store burst so read and write streams overlap.
// Block = 16 segs x 32 f2-lanes = 512 thr; grid = 32 b x 8 groups = 256.
// tb==0 carry-in = compressed[t=0] (virtual carry, exact y0 = c0).

typedef float vf2 __attribute__((ext_vector_type(2)));

namespace {
constexpr int kB    = 32;
constexpr int kT    = 4096;
constexpr int kF2   = 32;              // 64 floats = 32 vf2 per row
constexpr int kL    = 16;              // rows per segment
constexpr int kSEG  = 16;              // segments per tile
constexpr int kTBLK = kSEG * kL;       // 256 rows per tile
constexpr int kWALK = 2;               // tiles walked per block
constexpr int kGRP  = kWALK * kTBLK;   // 512 rows per block
constexpr int kNG   = kT / kGRP;       // 8 groups per b
constexpr int kLW   = 4;               // warm rows per thread
constexpr int kWROWS = kSEG * kLW;     // 64 warm-up rows
constexpr float kA   = 0.9f;
constexpr float kOmA = 1.0f - kA;

constexpr float apow(int n) { float r = 1.f; for (int i = 0; i < n; ++i) r *= 0.9f; return r; }
constexpr float kA16 = apow(kL);       // alpha^16
constexpr float kA4  = apow(kLW);      // alpha^4
}

__global__ __launch_bounds__(kSEG * kF2, 4) void cochlea_kernel(
    const vf2* __restrict__ spec,
    const vf2* __restrict__ ftune,
    const float* __restrict__ thr_p,
    const float* __restrict__ ratio_p,
    vf2* __restrict__ out)
{
    const int tid = threadIdx.x;
    const int f2  = tid & (kF2 - 1);
    const int seg = tid >> 5;                 // 0..15
    const int g   = blockIdx.x & (kNG - 1);
    const int b   = blockIdx.x >> 3;

    const float thr   = thr_p[0];
    const float ratio = ratio_p[0];
    const vf2 ft = ftune[f2];

    const size_t rowbase = (size_t)b * kT * kF2 + f2;
    const int tg0 = g * kGRP;

    auto comp = [&](vf2 x) -> vf2 {
        float ta = x.x * ft.x, tc = x.y * ft.y;
        float ca = fmaf(ta - thr, ratio, thr);
        float cc = fmaf(tc - thr, ratio, thr);
        vf2 v;
        v.x = (ta > thr) ? ca : ta;
        v.y = (tc > thr) ? cc : tc;
        return v;
    };

    __shared__ vf2 lds_c[kWALK][kSEG][kF2];
    __shared__ vf2 lds_w[kSEG][kF2];
    __shared__ vf2 lds_v0[kF2];

    // ---- warm-up: every seg scans 4 rows at tg0-64+seg*4 (g>0) ----
    vf2 yw = {0.f, 0.f};
    if (g > 0) {
        const vf2* wp = spec + rowbase + (size_t)(tg0 - kWROWS + seg * kLW) * kF2;
        vf2 wx[kLW];
        #pragma unroll
        for (int j = 0; j < kLW; ++j) wx[j] = wp[(size_t)j * kF2];
        #pragma unroll
        for (int j = 0; j < kLW; ++j) {
            vf2 v = comp(wx[j]);
            yw.x = fmaf(kA, yw.x, kOmA * v.x);
            yw.y = fmaf(kA, yw.y, kOmA * v.y);
        }
    }

    // ---- tile 0 local scan (y0 = 0), staged loads ----
    const vf2* sp0 = spec + rowbase + (size_t)(tg0 + seg * kL) * kF2;
    vf2 r[kL];
    vf2 y  = {0.f, 0.f};
    vf2 v0 = {0.f, 0.f};
    #pragma unroll
    for (int h = 0; h < 2; ++h) {
        vf2 xv[8];
        #pragma unroll
        for (int j = 0; j < 8; ++j) xv[j] = sp0[(size_t)(h * 8 + j) * kF2];
        #pragma unroll
        for (int j = 0; j < 8; ++j) {
            vf2 v = comp(xv[j]);
            if (h == 0 && j == 0) v0 = v;
            y.x = fmaf(kA, y.x, kOmA * v.x);
            y.y = fmaf(kA, y.y, kOmA * v.y);
            r[h * 8 + j] = y;
        }
    }
    lds_c[0][seg][f2] = y;
    lds_w[seg][f2] = yw;
    if (seg == 0) lds_v0[f2] = v0;
    __syncthreads();

    // ---- Hw = carry into tile 0: A4-Horner over 16 warm carries ----
    vf2 Hw;
    if (g == 0) {
        Hw = lds_v0[f2];                      // virtual carry: y_{-1} = c0
    } else {
        Hw = {0.f, 0.f};
        #pragma unroll
        for (int j = 0; j < kSEG; ++j) {
            vf2 w = lds_w[j][f2];
            Hw.x = fmaf(kA4, Hw.x, w.x);
            Hw.y = fmaf(kA4, Hw.y, w.y);
        }
    }

    // ---- tile-0 carry-ins: acc = Hw; Horner over carries (capture own);
    //      final acc = I1, the exact register carry into tile 1 ----
    vf2 acc = Hw, yin0 = {0.f, 0.f};
    #pragma unroll
    for (int j = 0; j < kSEG; ++j) {
        if (j == seg) yin0 = acc;
        vf2 c = lds_c[0][j][f2];
        acc.x = fmaf(kA16, acc.x, c.x);
        acc.y = fmaf(kA16, acc.y, c.y);
    }
    const vf2 I1 = acc;

    // ---- issue ALL tile-1 loads before tile-0 stores (overlap R/W) ----
    const vf2* sp1 = sp0 + (size_t)kTBLK * kF2;
    vf2 xv1[kL];
    #pragma unroll
    for (int j = 0; j < kL; ++j) xv1[j] = sp1[(size_t)j * kF2];

    // ---- fixup + store tile 0 ----
    vf2* op0 = out + rowbase + (size_t)(tg0 + seg * kL) * kF2;
    float ap = kA;
    #pragma unroll
    for (int j = 0; j < kL; ++j) {
        vf2 o;
        o.x = fmaxf(fmaf(ap, yin0.x, r[j].x), 0.f);
        o.y = fmaxf(fmaf(ap, yin0.y, r[j].y), 0.f);
        __builtin_nontemporal_store(o, op0 + (size_t)j * kF2);
        ap *= kA;
    }

    // ---- tile 1 local scan ----
    y = {0.f, 0.f};
    #pragma unroll
    for (int j = 0; j < kL; ++j) {
        vf2 v = comp(xv1[j]);
        y.x = fmaf(kA, y.x, kOmA * v.x);
        y.y = fmaf(kA, y.y, kOmA * v.y);
        r[j] = y;
    }
    lds_c[1][seg][f2] = y;
    __syncthreads();

    // ---- tile-1 carry-ins: acc = I1 (exact, in-register) ----
    vf2 acc1 = I1, yin1 = {0.f, 0.f};
    #pragma unroll
    for (int j = 0; j < kSEG; ++j) {
        if (j == seg) yin1 = acc1;
        vf2 c = lds_c[1][j][f2];
        acc1.x = fmaf(kA16, acc1.x, c.x);
        acc1.y = fmaf(kA16, acc1.y, c.y);
    }

    // ---- fixup + store tile 1 ----
    vf2* op1 = op0 + (size_t)kTBLK * kF2;
    ap = kA;
    #pragma unroll
    for (int j = 0; j < kL; ++j) {
        vf2 o;
        o.x = fmaxf(fmaf(ap, yin1.x, r[j].x), 0.f);
        o.y = fmaxf(fmaf(ap, yin1.y, r[j].y), 0.f);
        __builtin_nontemporal_store(o, op1 + (size_t)j * kF2);
        ap *= kA;
    }
}

extern "C" void kernel_launch(void* const* d_in, const int* in_sizes, int n_in,
                              void* d_out, int out_size, void* d_ws, size_t ws_size,
                              hipStream_t stream) {
    const vf2*   spec  = (const vf2*)d_in[0];
    const vf2*   ftune = (const vf2*)d_in[1];
    const float* thr   = (const float*)d_in[2];
    const float* ratio = (const float*)d_in[3];
    vf2* out = (vf2*)d_out;

    dim3 grid(kB * kNG), block(kSEG * kF2);   // 256 blocks x 512 threads
    cochlea_kernel<<<grid, block, 0, stream>>>(spec, ftune, thr, ratio, out);
}

// Round 8
// 13.584 us; speedup vs baseline: 5.9415x; 1.1850x over previous
//
#include <hip/hip_runtime.h>

// Cochlea: per-f compress + first-order IIR (alpha=0.9) along T + ReLU.
// B=32, T=4096, F=64.
//
// Round-8: same walk-2 algorithm as round 7 (register carry across tiles,
// 64-row uniform warm-up, alpha^64 ~ 1.2e-3 truncation), restructured for
// stream smoothness:
//  - F split in halves: block = 256 thr (16 segs x 16 f2), grid = 512
//    = 2 blocks/CU -> one block's store burst overlaps the other's loads.
//  - ALL 36 loads (warm + tile0 + tile1) issued before any compute: warm
//    latency no longer serialized ahead of the main stream (~150 VGPR ok).
//  - XCD-aware block index: all 16 blocks of a given b land on XCD b%8
//    (d%8 round-robin heuristic) so warm re-reads hit that XCD's L2
//    (1 MB input per b << 4 MB L2).
// tb==0 carry-in = compressed[t=0] (virtual carry, exact y0 = c0).

typedef float vf2 __attribute__((ext_vector_type(2)));

namespace {
constexpr int kB    = 32;
constexpr int kT    = 4096;
constexpr int kF2   = 32;              // full row = 32 vf2 (256 B)
constexpr int kFH   = 16;              // vf2 lanes per F-half
constexpr int kL    = 16;              // rows per segment
constexpr int kSEG  = 16;              // segments per tile
constexpr int kTBLK = kSEG * kL;       // 256 rows per tile
constexpr int kGRP  = 2 * kTBLK;       // 512 rows per block (walk 2)
constexpr int kNG   = kT / kGRP;       // 8 groups per b
constexpr int kLW   = 4;               // warm rows per thread
constexpr int kWROWS = kSEG * kLW;     // 64 warm-up rows
constexpr float kA   = 0.9f;
constexpr float kOmA = 1.0f - kA;

constexpr float apow(int n) { float r = 1.f; for (int i = 0; i < n; ++i) r *= 0.9f; return r; }
constexpr float kA16 = apow(kL);       // alpha^16
constexpr float kA4  = apow(kLW);      // alpha^4
}

__global__ __launch_bounds__(256, 2) void cochlea_kernel(
    const vf2* __restrict__ spec,
    const vf2* __restrict__ ftune,
    const float* __restrict__ thr_p,
    const float* __restrict__ ratio_p,
    vf2* __restrict__ out)
{
    const int tid = threadIdx.x;
    const int f2  = tid & (kFH - 1);
    const int seg = tid >> 4;                 // 0..15

    // XCD-aware decode: d%8 == b%8 -> all groups of b share one XCD L2.
    const int d    = blockIdx.x;
    const int blo  = d & 7;
    const int rest = d >> 3;                  // 0..63
    const int b    = ((rest >> 4) << 3) | blo;
    const int sub  = rest & 15;               // 0..15
    const int g    = sub >> 1;                // 0..7
    const int fh   = sub & 1;

    const float thr   = thr_p[0];
    const float ratio = ratio_p[0];
    const vf2 ft = ftune[fh * kFH + f2];

    const size_t rowbase = (size_t)b * kT * kF2 + fh * kFH + f2;
    const int tg0 = g * kGRP;

    auto comp = [&](vf2 x) -> vf2 {
        float ta = x.x * ft.x, tc = x.y * ft.y;
        float ca = fmaf(ta - thr, ratio, thr);
        float cc = fmaf(tc - thr, ratio, thr);
        vf2 v;
        v.x = (ta > thr) ? ca : ta;
        v.y = (tc > thr) ? cc : tc;
        return v;
    };

    // ---- issue ALL loads up front (warm + tile0 + tile1) ----
    const vf2* sp0 = spec + rowbase + (size_t)(tg0 + seg * kL) * kF2;
    const vf2* sp1 = sp0 + (size_t)kTBLK * kF2;

    vf2 wx[kLW];
    if (g > 0) {
        const vf2* wp = spec + rowbase + (size_t)(tg0 - kWROWS + seg * kLW) * kF2;
        #pragma unroll
        for (int j = 0; j < kLW; ++j) wx[j] = wp[(size_t)j * kF2];
    }
    vf2 xv0[kL];
    #pragma unroll
    for (int j = 0; j < kL; ++j) xv0[j] = sp0[(size_t)j * kF2];
    vf2 xv1[kL];
    #pragma unroll
    for (int j = 0; j < kL; ++j) xv1[j] = sp1[(size_t)j * kF2];

    // ---- warm-up scan (g>0): 4 rows per seg ----
    vf2 yw = {0.f, 0.f};
    if (g > 0) {
        #pragma unroll
        for (int j = 0; j < kLW; ++j) {
            vf2 v = comp(wx[j]);
            yw.x = fmaf(kA, yw.x, kOmA * v.x);
            yw.y = fmaf(kA, yw.y, kOmA * v.y);
        }
    }

    // ---- tile 0 local scan (y0 = 0) ----
    vf2 r[kL];
    vf2 y  = {0.f, 0.f};
    vf2 v0 = {0.f, 0.f};
    #pragma unroll
    for (int j = 0; j < kL; ++j) {
        vf2 v = comp(xv0[j]);
        if (j == 0) v0 = v;
        y.x = fmaf(kA, y.x, kOmA * v.x);
        y.y = fmaf(kA, y.y, kOmA * v.y);
        r[j] = y;
    }

    __shared__ vf2 lds_c[2][kSEG][kFH];
    __shared__ vf2 lds_w[kSEG][kFH];
    __shared__ vf2 lds_v0[kFH];
    lds_c[0][seg][f2] = y;
    lds_w[seg][f2] = yw;
    if (seg == 0) lds_v0[f2] = v0;
    __syncthreads();

    // ---- Hw = carry into tile 0 ----
    vf2 Hw;
    if (g == 0) {
        Hw = lds_v0[f2];                      // virtual carry: y_{-1} = c0
    } else {
        Hw = {0.f, 0.f};
        #pragma unroll
        for (int j = 0; j < kSEG; ++j) {
            vf2 w = lds_w[j][f2];
            Hw.x = fmaf(kA4, Hw.x, w.x);
            Hw.y = fmaf(kA4, Hw.y, w.y);
        }
    }

    // ---- tile-0 carry-ins (capture own) + exact register carry I1 ----
    vf2 acc = Hw, yin0 = {0.f, 0.f};
    #pragma unroll
    for (int j = 0; j < kSEG; ++j) {
        if (j == seg) yin0 = acc;
        vf2 c = lds_c[0][j][f2];
        acc.x = fmaf(kA16, acc.x, c.x);
        acc.y = fmaf(kA16, acc.y, c.y);
    }
    const vf2 I1 = acc;

    // ---- fixup + store tile 0 ----
    vf2* op0 = out + rowbase + (size_t)(tg0 + seg * kL) * kF2;
    float ap = kA;
    #pragma unroll
    for (int j = 0; j < kL; ++j) {
        vf2 o;
        o.x = fmaxf(fmaf(ap, yin0.x, r[j].x), 0.f);
        o.y = fmaxf(fmaf(ap, yin0.y, r[j].y), 0.f);
        __builtin_nontemporal_store(o, op0 + (size_t)j * kF2);
        ap *= kA;
    }

    // ---- tile 1 local scan ----
    y = {0.f, 0.f};
    #pragma unroll
    for (int j = 0; j < kL; ++j) {
        vf2 v = comp(xv1[j]);
        y.x = fmaf(kA, y.x, kOmA * v.x);
        y.y = fmaf(kA, y.y, kOmA * v.y);
        r[j] = y;
    }
    lds_c[1][seg][f2] = y;
    __syncthreads();

    // ---- tile-1 carry-ins from I1 (exact, in-register) ----
    vf2 acc1 = I1, yin1 = {0.f, 0.f};
    #pragma unroll
    for (int j = 0; j < kSEG; ++j) {
        if (j == seg) yin1 = acc1;
        vf2 c = lds_c[1][j][f2];
        acc1.x = fmaf(kA16, acc1.x, c.x);
        acc1.y = fmaf(kA16, acc1.y, c.y);
    }

    // ---- fixup + store tile 1 ----
    vf2* op1 = op0 + (size_t)kTBLK * kF2;
    ap = kA;
    #pragma unroll
    for (int j = 0; j < kL; ++j) {
        vf2 o;
        o.x = fmaxf(fmaf(ap, yin1.x, r[j].x), 0.f);
        o.y = fmaxf(fmaf(ap, yin1.y, r[j].y), 0.f);
        __builtin_nontemporal_store(o, op1 + (size_t)j * kF2);
        ap *= kA;
    }
}

extern "C" void kernel_launch(void* const* d_in, const int* in_sizes, int n_in,
                              void* d_out, int out_size, void* d_ws, size_t ws_size,
                              hipStream_t stream) {
    const vf2*   spec  = (const vf2*)d_in[0];
    const vf2*   ftune = (const vf2*)d_in[1];
    const float* thr   = (const float*)d_in[2];
    const float* ratio = (const float*)d_in[3];
    vf2* out = (vf2*)d_out;

    dim3 grid(kB * kNG * 2), block(kSEG * kFH);   // 512 blocks x 256 threads
    cochlea_kernel<<<grid, block, 0, stream>>>(spec, ftune, thr, ratio, out);
}